// Round 16
// baseline (130.599 us; speedup 1.0000x reference)
//
#include <hip/hip_runtime.h>
#include <stdint.h>

typedef __attribute__((ext_vector_type(8))) short bf8v;   // 8 bf16/f16 raw bits (4 VGPRs)
typedef __attribute__((ext_vector_type(4))) float f4v;
typedef __attribute__((ext_vector_type(16))) float f16v;
typedef __attribute__((ext_vector_type(4))) unsigned int u4v;

__device__ __forceinline__ unsigned short f2bf(float f) {
  unsigned int u = __float_as_uint(f);
  u += 0x7fffu + ((u >> 16) & 1u);   // round-to-nearest-even
  return (unsigned short)(u >> 16);
}

__device__ __forceinline__ unsigned short f2h(float f) {
  _Float16 h = (_Float16)f;
  return __builtin_bit_cast(unsigned short, h);
}

__device__ __forceinline__ float h2f(unsigned short s) {
  return (float)__builtin_bit_cast(_Float16, s);
}

__device__ __forceinline__ void gload16(const void* g, void* l) {
  __builtin_amdgcn_global_load_lds(
      (__attribute__((address_space(1))) void*)reinterpret_cast<uintptr_t>(g),
      (__attribute__((address_space(3))) void*)reinterpret_cast<uintptr_t>(l),
      16, 0, 0);
}

__device__ __forceinline__ unsigned cvtpk(float lo, float hi) {
  unsigned r;
  asm("v_cvt_pk_bf16_f32 %0, %1, %2" : "=v"(r) : "v"(lo), "v"(hi));
  return r;
}

// pairwise lane<->lane^32 exchange; with x=y=v: x={v.lo,v.lo}, y={v.hi,v.hi}
#define PAIR_SWAP(x, y) asm("v_permlane32_swap_b32 %0, %1" : "+v"(x), "+v"(y))

// ---------------- fp32 -> bf16 conversion (single fused launch, acts + weights) ----------------
__global__ __launch_bounds__(256) void cvt_all(
    const float* __restrict__ s0, const float* __restrict__ s1,
    const float* __restrict__ s2, const float* __restrict__ s3,
    const float* __restrict__ s4, const float* __restrict__ s5,
    const float* __restrict__ s6, unsigned short* __restrict__ dst) {
  const size_t NA = (size_t)1 << 22, NW = (size_t)1 << 20;
  size_t i = ((size_t)blockIdx.x * 256 + threadIdx.x) * 8;
  const float* src;
  size_t off;
  if (i < 3 * NA) {
    int a = (int)(i >> 22);
    src = (a == 0) ? s0 : (a == 1) ? s1 : s2;
    off = i & (NA - 1);
  } else {
    size_t j = i - 3 * NA;
    int a = (int)(j >> 20);
    src = (a == 0) ? s3 : (a == 1) ? s4 : (a == 2) ? s5 : s6;
    off = j & (NW - 1);
  }
  const f4v* sp = (const f4v*)(src + off);
  f4v x = sp[0], y = sp[1];
  bf8v r;
  r[0] = (short)f2bf(x[0]); r[1] = (short)f2bf(x[1]);
  r[2] = (short)f2bf(x[2]); r[3] = (short)f2bf(x[3]);
  r[4] = (short)f2bf(y[0]); r[5] = (short)f2bf(y[1]);
  r[6] = (short)f2bf(y[2]); r[7] = (short)f2bf(y[3]);
  *(bf8v*)(dst + i) = r;
}

// ---------------- 128xTNx(BK=32) bf16 GEMM body (m97 structure, gload_lds both operands) ----------------
// A: (4096,1024) bf16 row-major.  W: (1024,1024) bf16 row-major (n,k) = B^T.
// OMODE 0: out bf16 (B,H,S,64); A rows are (s*2+b).
// OMODE 1: out bf16 (B,H,64,S) [V pre-transposed]; A rows are (s*2+b).
// OMODE 2: out fp32 (S,B,D); A rows are (b*2048+s).
// Measured: TN=128 for qkv (42us; TN=64 regressed to 57 via L2 A-re-read);
// TN=64 for out_gemm (11.5us; runs alone on an L2-hot set).
template <int OMODE, int TN>
__device__ __forceinline__ void gemm_body(
    unsigned short* Al, unsigned short* Bl,
    const unsigned short* __restrict__ A, const unsigned short* __restrict__ W,
    const float* __restrict__ bias, void* __restrict__ out) {
  const int tid = threadIdx.x;
  const int w = tid >> 6, l = tid & 63;
  const int lr = l >> 4, lc = l & 15;
  const int m0 = blockIdx.x * 128, n0 = blockIdx.y * TN;
  const int wr = w >> 1, wc = w & 1;
  const int JW = TN / 32;
  const int BCPW = TN / 64;
  const int BBUF = TN * 32;

  f4v acc[4][JW];
#pragma unroll
  for (int i = 0; i < 4; i++)
#pragma unroll
    for (int j = 0; j < JW; j++) acc[i][j] = (f4v)(0.0f);

  const int NK = 32;
#pragma unroll
  for (int i = 0; i < 2; i++) {
    int chunk = w * 2 + i;
    int e = chunk * 512 + l * 8;
    int r = e >> 5, k = e & 31;
    gload16(A + (size_t)(m0 + r) * 1024 + k, Al + chunk * 512);
  }
#pragma unroll
  for (int i = 0; i < BCPW; i++) {
    int chunk = w * BCPW + i;
    int e = chunk * 512 + l * 8;
    int r = e >> 5, k = e & 31;
    gload16(W + (size_t)(n0 + r) * 1024 + k, Bl + chunk * 512);
  }

  for (int kk = 0; kk < NK; kk++) {
    const int cur = kk & 1;
    __syncthreads();
    if (kk + 1 < NK) {
#pragma unroll
      for (int i = 0; i < 2; i++) {
        int chunk = w * 2 + i;
        int e = chunk * 512 + l * 8;
        int r = e >> 5, k = (kk + 1) * 32 + (e & 31);
        gload16(A + (size_t)(m0 + r) * 1024 + k, Al + (cur ^ 1) * 4096 + chunk * 512);
      }
#pragma unroll
      for (int i = 0; i < BCPW; i++) {
        int chunk = w * BCPW + i;
        int e = chunk * 512 + l * 8;
        int r = e >> 5, k = (kk + 1) * 32 + (e & 31);
        gload16(W + (size_t)(n0 + r) * 1024 + k, Bl + (cur ^ 1) * BBUF + chunk * 512);
      }
    }
    bf8v av[4], bv[JW];
#pragma unroll
    for (int i = 0; i < 4; i++) {
      int row = wr * 64 + i * 16 + lc;
      av[i] = *(const bf8v*)(Al + cur * 4096 + row * 32 + lr * 8);
    }
#pragma unroll
    for (int j = 0; j < JW; j++) {
      int row = wc * (TN / 2) + j * 16 + lc;
      bv[j] = *(const bf8v*)(Bl + cur * BBUF + row * 32 + lr * 8);
    }
#pragma unroll
    for (int i = 0; i < 4; i++)
#pragma unroll
      for (int j = 0; j < JW; j++)
        acc[i][j] = __builtin_amdgcn_mfma_f32_16x16x32_bf16(av[i], bv[j], acc[i][j], 0, 0, 0);
  }

#pragma unroll
  for (int j = 0; j < JW; j++) {
    int n = n0 + wc * (TN / 2) + j * 16 + lc;
    float bj = bias[n];
#pragma unroll
    for (int i = 0; i < 4; i++) {
      int mb = m0 + wr * 64 + i * 16 + lr * 4;
#pragma unroll
      for (int q = 0; q < 4; q++) {
        float val = fmaxf(acc[i][j][q] + bj, 0.0f);
        int m = mb + q;
        if (OMODE == 2) {
          int s = m & 2047, b = m >> 11;
          ((float*)out)[(size_t)(s * 2 + b) * 1024 + n] = val;
        } else {
          int s = m >> 1, b = m & 1;
          int h = n >> 6, d = n & 63;
          if (OMODE == 0)
            ((unsigned short*)out)[((size_t)(b * 16 + h) * 2048 + s) * 64 + d] = f2bf(val);
          else
            ((unsigned short*)out)[((size_t)(b * 16 + h) * 64 + d) * 2048 + s] = f2bf(val);
        }
      }
    }
  }
}

__global__ __launch_bounds__(256) void qkv_gemm(
    const unsigned short* __restrict__ qA, const unsigned short* __restrict__ kA,
    const unsigned short* __restrict__ vA,
    const unsigned short* __restrict__ Wq, const unsigned short* __restrict__ Wk,
    const unsigned short* __restrict__ Wv,
    const float* __restrict__ bq, const float* __restrict__ bk,
    const float* __restrict__ bv,
    unsigned short* __restrict__ Qh, unsigned short* __restrict__ Kh,
    unsigned short* __restrict__ Vt) {
  __shared__ __align__(16) unsigned short Al[2 * 4096];
  __shared__ __align__(16) unsigned short Bl[2 * 4096];
  int z = blockIdx.z;
  if (z == 0)      gemm_body<0, 128>(Al, Bl, qA, Wq, bq, Qh);
  else if (z == 1) gemm_body<0, 128>(Al, Bl, kA, Wk, bk, Kh);
  else             gemm_body<1, 128>(Al, Bl, vA, Wv, bv, Vt);
}

__global__ __launch_bounds__(256) void out_gemm(
    const unsigned short* __restrict__ Y, const unsigned short* __restrict__ Wo,
    const float* __restrict__ bo, float* __restrict__ out) {
  __shared__ __align__(16) unsigned short Al[2 * 4096];
  __shared__ __align__(16) unsigned short Bl[2 * 2048];
  gemm_body<2, 64>(Al, Bl, Y, Wo, bo, out);
}

// ---------------- flash attention: dual-subtile waves, SPL=2, KVBLK=128 (R14 proven, ~40us) ----------------
__global__ __launch_bounds__(256, 2) void attn_kernel(
    const unsigned short* __restrict__ Qh, const unsigned short* __restrict__ Kh,
    const unsigned short* __restrict__ Vt,
    unsigned short* __restrict__ PO, float2* __restrict__ ML, int kvlen) {
  __shared__ __align__(16) unsigned short Kl[2][8192];
  __shared__ __align__(16) unsigned short Vl[2][8192];
  const int tid = threadIdx.x, w = tid >> 6, l = tid & 63;
  const int lo = l & 31, hi = l >> 5;
  const int bh = blockIdx.y;
  const int z = blockIdx.z;
  const int tbeg = z * kvlen, tend = tbeg + kvlen;
  const int q0 = blockIdx.x * 256 + w * 64;
  const size_t qkbase = (size_t)bh * 2048 * 64;
  const size_t vtbase = (size_t)bh * 64 * 2048;
  const float cs = 0.125f * 1.44269504088896341f;  // 1/sqrt(64) * log2(e)

  bf8v qf[2][4];
#pragma unroll
  for (int s = 0; s < 2; s++)
#pragma unroll
    for (int c = 0; c < 4; c++)
      qf[s][c] = *(const bf8v*)(Qh + qkbase + (size_t)(q0 + s * 32 + lo) * 64 + c * 16 + hi * 8);

  f16v oacc[2][2];
  oacc[0][0] = (f16v)(0.0f); oacc[0][1] = (f16v)(0.0f);
  oacc[1][0] = (f16v)(0.0f); oacc[1][1] = (f16v)(0.0f);
  float mrun[2] = {-1e30f, -1e30f};
  float lrun[2] = {0.0f, 0.0f};

  // LDS read addresses. K: [128][64] bf16, 128B rows, swizzle (row&7)<<4.
  // V^T: [64][128] bf16, 256B rows, swizzle (row&15)<<4.
  const int swk = (lo & 7) << 4;
  const int swv = (lo & 15) << 4;
  int akb[4], avb[2][4][2];
#pragma unroll
  for (int c = 0; c < 4; c++) akb[c] = lo * 128 + ((c * 32 + hi * 16) ^ swk);
#pragma unroll
  for (int dt = 0; dt < 2; dt++)
#pragma unroll
    for (int kvh = 0; kvh < 4; kvh++)
#pragma unroll
      for (int kc = 0; kc < 2; kc++)
        avb[dt][kvh][kc] = (dt * 32 + lo) * 256 + ((kvh * 64 + kc * 32 + hi * 16) ^ swv);

  // staging source elements (pre-swizzled: linear LDS dest + swizzled read)
  int stKE[4], stVD[4], stVKV[4];
#pragma unroll
  for (int i = 0; i < 4; i++) {
    int o = (w * 4 + i) * 1024 + l * 16;
    int rK = o >> 7;
    stKE[i] = (o ^ ((rK & 7) << 4)) >> 1;
    int rV = o >> 8;
    int eV = (o ^ ((rV & 15) << 4)) >> 1;
    stVD[i] = eV >> 7;
    stVKV[i] = eV & 127;
  }
  const char* KlB = (const char*)&Kl[0][0];
  const char* VlB = (const char*)&Vl[0][0];

  auto STAGE = [&](int buf, int t0) {
#pragma unroll
    for (int i = 0; i < 4; i++) {
      gload16(Kh + qkbase + (size_t)t0 * 64 + stKE[i], (char*)&Kl[buf][0] + (w * 4 + i) * 1024);
      gload16(Vt + vtbase + (size_t)stVD[i] * 2048 + t0 + stVKV[i], (char*)&Vl[buf][0] + (w * 4 + i) * 1024);
    }
  };

  auto COMPUTE = [&](int bo) {
#pragma unroll
    for (int kvh = 0; kvh < 4; kvh++) {
      bf8v kf[4];
#pragma unroll
      for (int c = 0; c < 4; c++)
        kf[c] = *(const bf8v*)(KlB + bo + kvh * 4096 + akb[c]);
      f16v sa = (f16v)(0.0f), sb = (f16v)(0.0f);
      __builtin_amdgcn_s_setprio(1);
#pragma unroll
      for (int c = 0; c < 4; c++) {
        sa = __builtin_amdgcn_mfma_f32_32x32x16_bf16(kf[c], qf[0][c], sa, 0, 0, 0);
        sb = __builtin_amdgcn_mfma_f32_32x32x16_bf16(kf[c], qf[1][c], sb, 0, 0, 0);
      }
      __builtin_amdgcn_s_setprio(0);
      bf8v vf[2][2];
#pragma unroll
      for (int dt = 0; dt < 2; dt++)
#pragma unroll
        for (int kc = 0; kc < 2; kc++)
          vf[dt][kc] = *(const bf8v*)(VlB + bo + avb[dt][kvh][kc]);

#pragma unroll
      for (int s = 0; s < 2; s++) {
        const f16v& sc16 = (s == 0) ? sa : sb;
        float t0 = fmaxf(fmaxf(sc16[0], sc16[1]), sc16[2]);
        float t1 = fmaxf(fmaxf(sc16[3], sc16[4]), sc16[5]);
        float t2 = fmaxf(fmaxf(sc16[6], sc16[7]), sc16[8]);
        float t3 = fmaxf(fmaxf(sc16[9], sc16[10]), sc16[11]);
        float t4 = fmaxf(fmaxf(sc16[12], sc16[13]), sc16[14]);
        float lm = fmaxf(fmaxf(fmaxf(t0, t1), fmaxf(t2, t3)), fmaxf(t4, sc16[15]));
        float msc = lm * cs;
        if (!__all(msc <= mrun[s] + 5.0f)) {
          float x = msc, y = msc;
          PAIR_SWAP(x, y);
          float pm = fmaxf(x, y);
          float mnew = fmaxf(mrun[s], pm);
          float scl = __builtin_amdgcn_exp2f(mrun[s] - mnew);
          lrun[s] *= scl;
#pragma unroll
          for (int dt = 0; dt < 2; dt++)
#pragma unroll
            for (int r = 0; r < 16; r++) oacc[s][dt][r] *= scl;
          mrun[s] = mnew;
        }
        float p[16];
#pragma unroll
        for (int r = 0; r < 16; r++)
          p[r] = __builtin_amdgcn_exp2f(sc16[r] * cs - mrun[s]);
        float s01 = (p[0] + p[1]) + (p[2] + p[3]);
        float s23 = (p[4] + p[5]) + (p[6] + p[7]);
        float s45 = (p[8] + p[9]) + (p[10] + p[11]);
        float s67 = (p[12] + p[13]) + (p[14] + p[15]);
        lrun[s] += (s01 + s23) + (s45 + s67);
        bf8v pf[2];
#pragma unroll
        for (int kc = 0; kc < 2; kc++) {
          unsigned a0 = cvtpk(p[kc * 8 + 0], p[kc * 8 + 1]);
          unsigned a1 = cvtpk(p[kc * 8 + 2], p[kc * 8 + 3]);
          unsigned b0 = cvtpk(p[kc * 8 + 4], p[kc * 8 + 5]);
          unsigned b1 = cvtpk(p[kc * 8 + 6], p[kc * 8 + 7]);
          PAIR_SWAP(a0, b0);
          PAIR_SWAP(a1, b1);
          u4v pw;
          pw[0] = a0; pw[1] = a1; pw[2] = b0; pw[3] = b1;
          pf[kc] = __builtin_bit_cast(bf8v, pw);
        }
        __builtin_amdgcn_s_setprio(1);
#pragma unroll
        for (int dt = 0; dt < 2; dt++)
#pragma unroll
          for (int kc = 0; kc < 2; kc++)
            oacc[s][dt] = __builtin_amdgcn_mfma_f32_32x32x16_bf16(vf[dt][kc], pf[kc],
                                                                 oacc[s][dt], 0, 0, 0);
        __builtin_amdgcn_s_setprio(0);
      }
    }
  };

  STAGE(0, tbeg);
  __syncthreads();
#pragma unroll 1
  for (int t0 = tbeg; t0 < tend; t0 += 256) {
    STAGE(1, t0 + 128);
    COMPUTE(0);
    __syncthreads();
    if (t0 + 256 < tend) STAGE(0, t0 + 256);
    COMPUTE(16384);
    __syncthreads();
  }

  // epilogue: pair-total sums, NORMALIZE, write fp16 partials.
#pragma unroll
  for (int s = 0; s < 2; s++) {
    float x = lrun[s], y = lrun[s];
    PAIR_SWAP(x, y);
    float lt = x + y;
    float inv = 1.0f / lt;
    int q = q0 + s * 32 + lo;
    size_t prow = (size_t)(z * 32 + bh) * 2048 + q;
    if (hi == 0) ML[prow] = float2{mrun[s], lt};
    unsigned short* pp = PO + prow * 64;
#pragma unroll
    for (int dt = 0; dt < 2; dt++)
#pragma unroll
      for (int r = 0; r < 16; r++) {
        int d = dt * 32 + (r & 3) + 8 * (r >> 2) + 4 * hi;
        pp[d] = f2h(oacc[s][dt][r] * inv);
      }
  }
}

// ---------------- combine 2 normalized fp16 partials -> Y (B,S,D) bf16 ----------------
__global__ __launch_bounds__(256) void combine_kernel(
    const unsigned short* __restrict__ PO, const float2* __restrict__ ML,
    unsigned short* __restrict__ Y) {
  int idx = blockIdx.x * 256 + threadIdx.x;
  int row = idx >> 1, hr = idx & 1;
  int bh = row >> 11, q = row & 2047;
  float2 ml0 = ML[row], ml1 = ML[65536 + row];
  float M = fmaxf(ml0.x, ml1.x);
  float w0 = ml0.y * __builtin_amdgcn_exp2f(ml0.x - M);
  float w1 = ml1.y * __builtin_amdgcn_exp2f(ml1.x - M);
  float invW = 1.0f / (w0 + w1);
  w0 *= invW; w1 *= invW;
  int b = bh >> 4, h = bh & 15;
  unsigned short* yp = Y + (((size_t)(b * 2048 + q)) << 10) + h * 64 + hr * 32;
  const unsigned short* p0 = PO + (size_t)row * 64 + hr * 32;
  const unsigned short* p1 = PO + ((size_t)65536 + row) * 64 + hr * 32;
#pragma unroll
  for (int g = 0; g < 4; g++) {
    bf8v v0 = *(const bf8v*)(p0 + g * 8);
    bf8v v1 = *(const bf8v*)(p1 + g * 8);
    bf8v r;
#pragma unroll
    for (int j = 0; j < 8; j++)
      r[j] = (short)f2bf(h2f((unsigned short)v0[j]) * w0 +
                         h2f((unsigned short)v1[j]) * w1);
    *(bf8v*)(yp + g * 8) = r;
  }
}

// ---------------- launch ----------------
extern "C" void kernel_launch(void* const* d_in, const int* in_sizes, int n_in,
                              void* d_out, int out_size, void* d_ws, size_t ws_size,
                              hipStream_t stream) {
  const float* q  = (const float*)d_in[0];
  const float* k  = (const float*)d_in[1];
  const float* v  = (const float*)d_in[2];
  const float* Wq = (const float*)d_in[3];
  const float* Wk = (const float*)d_in[4];
  const float* Wv = (const float*)d_in[5];
  const float* Wo = (const float*)d_in[6];
  const float* bq = (const float*)d_in[7];
  const float* bk = (const float*)d_in[8];
  const float* bv = (const float*)d_in[9];
  const float* bo = (const float*)d_in[10];

  const size_t NA = (size_t)4096 * 1024;   // 4M elems
  const size_t NW = (size_t)1024 * 1024;
  unsigned short* qA  = (unsigned short*)d_ws;   // cvt dst: q,k,v,Wq,Wk,Wv,Wo contiguous
  unsigned short* kA  = qA  + NA;
  unsigned short* vA  = kA  + NA;
  unsigned short* WqB = vA  + NA;
  unsigned short* WkB = WqB + NW;
  unsigned short* WvB = WkB + NW;
  unsigned short* WoB = WvB + NW;
  unsigned short* Qh  = WoB + NW;
  unsigned short* Kh  = Qh  + NA;
  unsigned short* Vt  = Kh  + NA;
  unsigned short* Y   = Vt  + NA;

  // attention partials overlay the dead qA/kA/vA region (inputs consumed by then)
  unsigned short* PO = qA;                 // 2 * 4M fp16 = 16 MB
  float2*         ML = (float2*)vA;        // 2 * 64K float2 = 1 MB

  cvt_all<<<dim3(8192), 256, 0, stream>>>(q, k, v, Wq, Wk, Wv, Wo, qA);

  qkv_gemm<<<dim3(32, 8, 3), 256, 0, stream>>>(qA, kA, vA, WqB, WkB, WvB,
                                               bq, bk, bv, Qh, Kh, Vt);
  attn_kernel<<<dim3(8, 32, 2), 256, 0, stream>>>(Qh, Kh, Vt, PO, ML, 1024);
  combine_kernel<<<dim3(512), 256, 0, stream>>>(PO, ML, Y);
  out_gemm<<<dim3(32, 16), 256, 0, stream>>>(Y, WoB, bo, (float*)d_out);
}

// Round 17
// 123.073 us; speedup vs baseline: 1.0612x; 1.0612x over previous
//
#include <hip/hip_runtime.h>
#include <stdint.h>

typedef __attribute__((ext_vector_type(8))) short bf8v;   // 8 bf16/f16 raw bits (4 VGPRs)
typedef __attribute__((ext_vector_type(4))) float f4v;
typedef __attribute__((ext_vector_type(16))) float f16v;
typedef __attribute__((ext_vector_type(4))) unsigned int u4v;

__device__ __forceinline__ unsigned short f2bf(float f) {
  unsigned int u = __float_as_uint(f);
  u += 0x7fffu + ((u >> 16) & 1u);   // round-to-nearest-even
  return (unsigned short)(u >> 16);
}

__device__ __forceinline__ unsigned short f2h(float f) {
  _Float16 h = (_Float16)f;
  return __builtin_bit_cast(unsigned short, h);
}

__device__ __forceinline__ float h2f(unsigned short s) {
  return (float)__builtin_bit_cast(_Float16, s);
}

__device__ __forceinline__ void gload16(const void* g, void* l) {
  __builtin_amdgcn_global_load_lds(
      (__attribute__((address_space(1))) void*)reinterpret_cast<uintptr_t>(g),
      (__attribute__((address_space(3))) void*)reinterpret_cast<uintptr_t>(l),
      16, 0, 0);
}

__device__ __forceinline__ unsigned cvtpk(float lo, float hi) {
  unsigned r;
  asm("v_cvt_pk_bf16_f32 %0, %1, %2" : "=v"(r) : "v"(lo), "v"(hi));
  return r;
}

// pairwise lane<->lane^32 exchange; with x=y=v: x={v.lo,v.lo}, y={v.hi,v.hi}
#define PAIR_SWAP(x, y) asm("v_permlane32_swap_b32 %0, %1" : "+v"(x), "+v"(y))

// ---------------- fp32 -> bf16 conversion: WEIGHTS ONLY (4 x 1M elems) ----------------
__global__ __launch_bounds__(256) void cvt_w(
    const float* __restrict__ s0, const float* __restrict__ s1,
    const float* __restrict__ s2, const float* __restrict__ s3,
    unsigned short* __restrict__ dst) {
  const size_t NW = (size_t)1 << 20;
  size_t i = ((size_t)blockIdx.x * 256 + threadIdx.x) * 8;
  int a = (int)(i >> 20);
  const float* src = (a == 0) ? s0 : (a == 1) ? s1 : (a == 2) ? s2 : s3;
  size_t off = i & (NW - 1);
  const f4v* sp = (const f4v*)(src + off);
  f4v x = sp[0], y = sp[1];
  bf8v r;
  r[0] = (short)f2bf(x[0]); r[1] = (short)f2bf(x[1]);
  r[2] = (short)f2bf(x[2]); r[3] = (short)f2bf(x[3]);
  r[4] = (short)f2bf(y[0]); r[5] = (short)f2bf(y[1]);
  r[6] = (short)f2bf(y[2]); r[7] = (short)f2bf(y[3]);
  *(bf8v*)(dst + i) = r;
}

// ---------------- qkv GEMM: fused fp32-A cvt, TN=128, depth-1 (R11 measured best) ----------------
// A: (4096,1024) fp32 row-major (rows m = s*2+b).  W: (1024,1024) bf16 (n,k).
// Depth-1 reg-staged A (load -> cvt_pk -> ds_write within one K-step); depth-2
// fails (compiler vmcnt(0)-before-barrier drains deep prefetches, R14).
// TN=64 fails (2x A re-reads saturate L2, R12). fp32-in-LDS fails (R10).
// OMODE 0: out bf16 (B,H,S,64).  OMODE 1: out bf16 (B,H,64,S) [V transposed].
template <int OMODE>
__device__ __forceinline__ void gemmA32r_body(
    unsigned short* Al, unsigned short* Bl,
    const float* __restrict__ A, const unsigned short* __restrict__ W,
    const float* __restrict__ bias, unsigned short* __restrict__ out) {
  const int tid = threadIdx.x;
  const int w = tid >> 6, l = tid & 63;
  const int lr = l >> 4, lc = l & 15;
  const int m0 = blockIdx.x * 128, n0 = blockIdx.y * 128;
  const int wr = w >> 1, wc = w & 1;

  f4v acc[4][4];
#pragma unroll
  for (int i = 0; i < 4; i++)
#pragma unroll
    for (int j = 0; j < 4; j++) acc[i][j] = (f4v)(0.0f);

  int eA[2], rA[2], kA[2];
#pragma unroll
  for (int i = 0; i < 2; i++) {
    int chunk = w * 2 + i;
    eA[i] = chunk * 512 + l * 8;
    rA[i] = eA[i] >> 5;
    kA[i] = eA[i] & 31;
  }

  const int NK = 32;
  f4v ar[2][2];

  auto A_LOAD = [&](int kk) {
#pragma unroll
    for (int i = 0; i < 2; i++) {
      const float* s = A + (size_t)(m0 + rA[i]) * 1024 + kk * 32 + kA[i];
      ar[i][0] = *(const f4v*)s;
      ar[i][1] = *(const f4v*)(s + 4);
    }
  };
  auto A_WRITE = [&](int buf) {
#pragma unroll
    for (int i = 0; i < 2; i++) {
      u4v aw;
      aw[0] = cvtpk(ar[i][0][0], ar[i][0][1]);
      aw[1] = cvtpk(ar[i][0][2], ar[i][0][3]);
      aw[2] = cvtpk(ar[i][1][0], ar[i][1][1]);
      aw[3] = cvtpk(ar[i][1][2], ar[i][1][3]);
      *(bf8v*)(Al + buf * 4096 + eA[i]) = __builtin_bit_cast(bf8v, aw);
    }
  };
  auto B_STAGE = [&](int buf, int kk) {
#pragma unroll
    for (int i = 0; i < 2; i++) {
      int chunk = w * 2 + i;
      int e = chunk * 512 + l * 8;
      int r = e >> 5, k = e & 31;
      gload16(W + (size_t)(n0 + r) * 1024 + kk * 32 + k, Bl + buf * 4096 + chunk * 512);
    }
  };

  // prologue: stage kk=0 into buffer 0
  A_LOAD(0);
  B_STAGE(0, 0);
  A_WRITE(0);
  __syncthreads();

  for (int kk = 0; kk < NK; kk++) {
    const int cur = kk & 1;
    const bool more = (kk + 1 < NK);
    if (more) {
      B_STAGE(cur ^ 1, kk + 1);
      A_LOAD(kk + 1);            // latency hides under the MFMAs below
    }
    bf8v av[4], bv[4];
#pragma unroll
    for (int i = 0; i < 4; i++) {
      int row = wr * 64 + i * 16 + lc;
      av[i] = *(const bf8v*)(Al + cur * 4096 + row * 32 + lr * 8);
    }
#pragma unroll
    for (int j = 0; j < 4; j++) {
      int row = wc * 64 + j * 16 + lc;
      bv[j] = *(const bf8v*)(Bl + cur * 4096 + row * 32 + lr * 8);
    }
#pragma unroll
    for (int i = 0; i < 4; i++)
#pragma unroll
      for (int j = 0; j < 4; j++)
        acc[i][j] = __builtin_amdgcn_mfma_f32_16x16x32_bf16(av[i], bv[j], acc[i][j], 0, 0, 0);
    if (more) A_WRITE(cur ^ 1);  // cur^1 not read this iter; barrier orders for next
    __syncthreads();
  }

  // epilogue: bias + ReLU + layout store
#pragma unroll
  for (int j = 0; j < 4; j++) {
    int n = n0 + wc * 64 + j * 16 + lc;
    float bj = bias[n];
#pragma unroll
    for (int i = 0; i < 4; i++) {
      int mb = m0 + wr * 64 + i * 16 + lr * 4;
#pragma unroll
      for (int q = 0; q < 4; q++) {
        float val = fmaxf(acc[i][j][q] + bj, 0.0f);
        int m = mb + q;
        int s = m >> 1, b = m & 1;
        int h = n >> 6, d = n & 63;
        if (OMODE == 0)
          out[((size_t)(b * 16 + h) * 2048 + s) * 64 + d] = f2bf(val);
        else
          out[((size_t)(b * 16 + h) * 64 + d) * 2048 + s] = f2bf(val);
      }
    }
  }
}

__global__ __launch_bounds__(256) void qkv_gemm(
    const float* __restrict__ qA, const float* __restrict__ kA,
    const float* __restrict__ vA,
    const unsigned short* __restrict__ Wq, const unsigned short* __restrict__ Wk,
    const unsigned short* __restrict__ Wv,
    const float* __restrict__ bq, const float* __restrict__ bk,
    const float* __restrict__ bv,
    unsigned short* __restrict__ Qh, unsigned short* __restrict__ Kh,
    unsigned short* __restrict__ Vt) {
  __shared__ __align__(16) unsigned short Al[2 * 4096];   // 16 KB
  __shared__ __align__(16) unsigned short Bl[2 * 4096];   // 16 KB
  int z = blockIdx.z;
  if (z == 0)      gemmA32r_body<0>(Al, Bl, qA, Wq, bq, Qh);
  else if (z == 1) gemmA32r_body<0>(Al, Bl, kA, Wk, bk, Kh);
  else             gemmA32r_body<1>(Al, Bl, vA, Wv, bv, Vt);
}

// ---------------- bf16-A GEMM body (m97 structure), used by out_gemm ----------------
template <int TN>
__device__ __forceinline__ void gemm_body2(
    unsigned short* Al, unsigned short* Bl,
    const unsigned short* __restrict__ A, const unsigned short* __restrict__ W,
    const float* __restrict__ bias, float* __restrict__ out) {
  const int tid = threadIdx.x;
  const int w = tid >> 6, l = tid & 63;
  const int lr = l >> 4, lc = l & 15;
  const int m0 = blockIdx.x * 128, n0 = blockIdx.y * TN;
  const int wr = w >> 1, wc = w & 1;
  const int JW = TN / 32;
  const int BCPW = TN / 64;
  const int BBUF = TN * 32;

  f4v acc[4][JW];
#pragma unroll
  for (int i = 0; i < 4; i++)
#pragma unroll
    for (int j = 0; j < JW; j++) acc[i][j] = (f4v)(0.0f);

  const int NK = 32;
#pragma unroll
  for (int i = 0; i < 2; i++) {
    int chunk = w * 2 + i;
    int e = chunk * 512 + l * 8;
    int r = e >> 5, k = e & 31;
    gload16(A + (size_t)(m0 + r) * 1024 + k, Al + chunk * 512);
  }
#pragma unroll
  for (int i = 0; i < BCPW; i++) {
    int chunk = w * BCPW + i;
    int e = chunk * 512 + l * 8;
    int r = e >> 5, k = e & 31;
    gload16(W + (size_t)(n0 + r) * 1024 + k, Bl + chunk * 512);
  }

  for (int kk = 0; kk < NK; kk++) {
    const int cur = kk & 1;
    __syncthreads();
    if (kk + 1 < NK) {
#pragma unroll
      for (int i = 0; i < 2; i++) {
        int chunk = w * 2 + i;
        int e = chunk * 512 + l * 8;
        int r = e >> 5, k = (kk + 1) * 32 + (e & 31);
        gload16(A + (size_t)(m0 + r) * 1024 + k, Al + (cur ^ 1) * 4096 + chunk * 512);
      }
#pragma unroll
      for (int i = 0; i < BCPW; i++) {
        int chunk = w * BCPW + i;
        int e = chunk * 512 + l * 8;
        int r = e >> 5, k = (kk + 1) * 32 + (e & 31);
        gload16(W + (size_t)(n0 + r) * 1024 + k, Bl + (cur ^ 1) * BBUF + chunk * 512);
      }
    }
    bf8v av[4], bv[JW];
#pragma unroll
    for (int i = 0; i < 4; i++) {
      int row = wr * 64 + i * 16 + lc;
      av[i] = *(const bf8v*)(Al + cur * 4096 + row * 32 + lr * 8);
    }
#pragma unroll
    for (int j = 0; j < JW; j++) {
      int row = wc * (TN / 2) + j * 16 + lc;
      bv[j] = *(const bf8v*)(Bl + cur * BBUF + row * 32 + lr * 8);
    }
#pragma unroll
    for (int i = 0; i < 4; i++)
#pragma unroll
      for (int j = 0; j < JW; j++)
        acc[i][j] = __builtin_amdgcn_mfma_f32_16x16x32_bf16(av[i], bv[j], acc[i][j], 0, 0, 0);
  }

#pragma unroll
  for (int j = 0; j < JW; j++) {
    int n = n0 + wc * (TN / 2) + j * 16 + lc;
    float bj = bias[n];
#pragma unroll
    for (int i = 0; i < 4; i++) {
      int mb = m0 + wr * 64 + i * 16 + lr * 4;
#pragma unroll
      for (int q = 0; q < 4; q++) {
        float val = fmaxf(acc[i][j][q] + bj, 0.0f);
        int m = mb + q;
        int s = m & 2047, b = m >> 11;          // A rows are b*2048+s
        out[(size_t)(s * 2 + b) * 1024 + n] = val;
      }
    }
  }
}

__global__ __launch_bounds__(256) void out_gemm(
    const unsigned short* __restrict__ Y, const unsigned short* __restrict__ Wo,
    const float* __restrict__ bo, float* __restrict__ out) {
  __shared__ __align__(16) unsigned short Al[2 * 4096];
  __shared__ __align__(16) unsigned short Bl[2 * 2048];
  gemm_body2<64>(Al, Bl, Y, Wo, bo, out);
}

// ---------------- flash attention (measured best: dual-subtile waves, SPL=2, KVBLK=64) ----------------
__global__ __launch_bounds__(256, 2) void attn_kernel(
    const unsigned short* __restrict__ Qh, const unsigned short* __restrict__ Kh,
    const unsigned short* __restrict__ Vt,
    unsigned short* __restrict__ PO, float2* __restrict__ ML, int kvlen) {
  __shared__ __align__(16) unsigned short Kl[2][4096];
  __shared__ __align__(16) unsigned short Vl[2][4096];
  const int tid = threadIdx.x, w = tid >> 6, l = tid & 63;
  const int lo = l & 31, hi = l >> 5;
  const int bh = blockIdx.y;
  const int z = blockIdx.z;
  const int tbeg = z * kvlen, tend = tbeg + kvlen;
  const int q0 = blockIdx.x * 256 + w * 64;
  const size_t qkbase = (size_t)bh * 2048 * 64;
  const size_t vtbase = (size_t)bh * 64 * 2048;
  const float cs = 0.125f * 1.44269504088896341f;  // 1/sqrt(64) * log2(e)

  bf8v qf[2][4];
#pragma unroll
  for (int s = 0; s < 2; s++)
#pragma unroll
    for (int c = 0; c < 4; c++)
      qf[s][c] = *(const bf8v*)(Qh + qkbase + (size_t)(q0 + s * 32 + lo) * 64 + c * 16 + hi * 8);

  f16v oacc[2][2];
  oacc[0][0] = (f16v)(0.0f); oacc[0][1] = (f16v)(0.0f);
  oacc[1][0] = (f16v)(0.0f); oacc[1][1] = (f16v)(0.0f);
  float mrun[2] = {-1e30f, -1e30f};
  float lrun[2] = {0.0f, 0.0f};

  const int swl = (lo & 7) << 4;
  int akb[4], avb[2][2][2];
#pragma unroll
  for (int c = 0; c < 4; c++) akb[c] = lo * 128 + ((c * 32 + hi * 16) ^ swl);
#pragma unroll
  for (int dt = 0; dt < 2; dt++)
#pragma unroll
    for (int kvh = 0; kvh < 2; kvh++)
#pragma unroll
      for (int kc = 0; kc < 2; kc++)
        avb[dt][kvh][kc] = (dt * 32 + lo) * 128 + ((kvh * 64 + kc * 32 + hi * 16) ^ swl);

  int stE[2], stD[2], stKV[2];
#pragma unroll
  for (int i = 0; i < 2; i++) {
    int o = (w * 2 + i) * 1024 + l * 16;
    int row = o >> 7;
    stE[i] = (o ^ ((row & 7) << 4)) >> 1;
    stD[i] = stE[i] >> 6;
    stKV[i] = stE[i] & 63;
  }
  const char* KlB = (const char*)&Kl[0][0];
  const char* VlB = (const char*)&Vl[0][0];

  auto STAGE = [&](int buf, int t0) {
#pragma unroll
    for (int i = 0; i < 2; i++) {
      gload16(Kh + qkbase + (size_t)t0 * 64 + stE[i], (char*)&Kl[buf][0] + (w * 2 + i) * 1024);
      gload16(Vt + vtbase + (size_t)stD[i] * 2048 + t0 + stKV[i], (char*)&Vl[buf][0] + (w * 2 + i) * 1024);
    }
  };

  auto COMPUTE = [&](int bo) {
#pragma unroll
    for (int kvh = 0; kvh < 2; kvh++) {
      bf8v kf[4];
#pragma unroll
      for (int c = 0; c < 4; c++)
        kf[c] = *(const bf8v*)(KlB + bo + kvh * 4096 + akb[c]);
      f16v sa = (f16v)(0.0f), sb = (f16v)(0.0f);
      __builtin_amdgcn_s_setprio(1);
#pragma unroll
      for (int c = 0; c < 4; c++) {
        sa = __builtin_amdgcn_mfma_f32_32x32x16_bf16(kf[c], qf[0][c], sa, 0, 0, 0);
        sb = __builtin_amdgcn_mfma_f32_32x32x16_bf16(kf[c], qf[1][c], sb, 0, 0, 0);
      }
      __builtin_amdgcn_s_setprio(0);
      bf8v vf[2][2];
#pragma unroll
      for (int dt = 0; dt < 2; dt++)
#pragma unroll
        for (int kc = 0; kc < 2; kc++)
          vf[dt][kc] = *(const bf8v*)(VlB + bo + avb[dt][kvh][kc]);

#pragma unroll
      for (int s = 0; s < 2; s++) {
        const f16v& sc16 = (s == 0) ? sa : sb;
        float t0 = fmaxf(fmaxf(sc16[0], sc16[1]), sc16[2]);
        float t1 = fmaxf(fmaxf(sc16[3], sc16[4]), sc16[5]);
        float t2 = fmaxf(fmaxf(sc16[6], sc16[7]), sc16[8]);
        float t3 = fmaxf(fmaxf(sc16[9], sc16[10]), sc16[11]);
        float t4 = fmaxf(fmaxf(sc16[12], sc16[13]), sc16[14]);
        float lm = fmaxf(fmaxf(fmaxf(t0, t1), fmaxf(t2, t3)), fmaxf(t4, sc16[15]));
        float msc = lm * cs;
        if (!__all(msc <= mrun[s] + 5.0f)) {
          float x = msc, y = msc;
          PAIR_SWAP(x, y);
          float pm = fmaxf(x, y);
          float mnew = fmaxf(mrun[s], pm);
          float scl = __builtin_amdgcn_exp2f(mrun[s] - mnew);
          lrun[s] *= scl;
#pragma unroll
          for (int dt = 0; dt < 2; dt++)
#pragma unroll
            for (int r = 0; r < 16; r++) oacc[s][dt][r] *= scl;
          mrun[s] = mnew;
        }
        float p[16];
#pragma unroll
        for (int r = 0; r < 16; r++)
          p[r] = __builtin_amdgcn_exp2f(sc16[r] * cs - mrun[s]);
        float s01 = (p[0] + p[1]) + (p[2] + p[3]);
        float s23 = (p[4] + p[5]) + (p[6] + p[7]);
        float s45 = (p[8] + p[9]) + (p[10] + p[11]);
        float s67 = (p[12] + p[13]) + (p[14] + p[15]);
        lrun[s] += (s01 + s23) + (s45 + s67);
        bf8v pf[2];
#pragma unroll
        for (int kc = 0; kc < 2; kc++) {
          unsigned a0 = cvtpk(p[kc * 8 + 0], p[kc * 8 + 1]);
          unsigned a1 = cvtpk(p[kc * 8 + 2], p[kc * 8 + 3]);
          unsigned b0 = cvtpk(p[kc * 8 + 4], p[kc * 8 + 5]);
          unsigned b1 = cvtpk(p[kc * 8 + 6], p[kc * 8 + 7]);
          PAIR_SWAP(a0, b0);
          PAIR_SWAP(a1, b1);
          u4v pw;
          pw[0] = a0; pw[1] = a1; pw[2] = b0; pw[3] = b1;
          pf[kc] = __builtin_bit_cast(bf8v, pw);
        }
        __builtin_amdgcn_s_setprio(1);
#pragma unroll
        for (int dt = 0; dt < 2; dt++)
#pragma unroll
          for (int kc = 0; kc < 2; kc++)
            oacc[s][dt] = __builtin_amdgcn_mfma_f32_32x32x16_bf16(vf[dt][kc], pf[kc],
                                                                 oacc[s][dt], 0, 0, 0);
        __builtin_amdgcn_s_setprio(0);
      }
    }
  };

  STAGE(0, tbeg);
  __syncthreads();
#pragma unroll 1
  for (int t0 = tbeg; t0 < tend; t0 += 128) {
    STAGE(1, t0 + 64);
    COMPUTE(0);
    __syncthreads();
    if (t0 + 128 < tend) STAGE(0, t0 + 128);
    COMPUTE(8192);
    __syncthreads();
  }

  // epilogue: pair-total sums, NORMALIZE, write fp16 partials.
#pragma unroll
  for (int s = 0; s < 2; s++) {
    float x = lrun[s], y = lrun[s];
    PAIR_SWAP(x, y);
    float lt = x + y;
    float inv = 1.0f / lt;
    int q = q0 + s * 32 + lo;
    size_t prow = (size_t)(z * 32 + bh) * 2048 + q;
    if (hi == 0) ML[prow] = float2{mrun[s], lt};
    unsigned short* pp = PO + prow * 64;
#pragma unroll
    for (int dt = 0; dt < 2; dt++)
#pragma unroll
      for (int r = 0; r < 16; r++) {
        int d = dt * 32 + (r & 3) + 8 * (r >> 2) + 4 * hi;
        pp[d] = f2h(oacc[s][dt][r] * inv);
      }
  }
}

// ---------------- combine 2 normalized fp16 partials -> Y (B,S,D) bf16 ----------------
__global__ __launch_bounds__(256) void combine_kernel(
    const unsigned short* __restrict__ PO, const float2* __restrict__ ML,
    unsigned short* __restrict__ Y) {
  int idx = blockIdx.x * 256 + threadIdx.x;
  int row = idx >> 1, hr = idx & 1;
  int bh = row >> 11, q = row & 2047;
  float2 ml0 = ML[row], ml1 = ML[65536 + row];
  float M = fmaxf(ml0.x, ml1.x);
  float w0 = ml0.y * __builtin_amdgcn_exp2f(ml0.x - M);
  float w1 = ml1.y * __builtin_amdgcn_exp2f(ml1.x - M);
  float invW = 1.0f / (w0 + w1);
  w0 *= invW; w1 *= invW;
  int b = bh >> 4, h = bh & 15;
  unsigned short* yp = Y + (((size_t)(b * 2048 + q)) << 10) + h * 64 + hr * 32;
  const unsigned short* p0 = PO + (size_t)row * 64 + hr * 32;
  const unsigned short* p1 = PO + ((size_t)65536 + row) * 64 + hr * 32;
#pragma unroll
  for (int g = 0; g < 4; g++) {
    bf8v v0 = *(const bf8v*)(p0 + g * 8);
    bf8v v1 = *(const bf8v*)(p1 + g * 8);
    bf8v r;
#pragma unroll
    for (int j = 0; j < 8; j++)
      r[j] = (short)f2bf(h2f((unsigned short)v0[j]) * w0 +
                         h2f((unsigned short)v1[j]) * w1);
    *(bf8v*)(yp + g * 8) = r;
  }
}

// ---------------- launch ----------------
extern "C" void kernel_launch(void* const* d_in, const int* in_sizes, int n_in,
                              void* d_out, int out_size, void* d_ws, size_t ws_size,
                              hipStream_t stream) {
  const float* q  = (const float*)d_in[0];
  const float* k  = (const float*)d_in[1];
  const float* v  = (const float*)d_in[2];
  const float* Wq = (const float*)d_in[3];
  const float* Wk = (const float*)d_in[4];
  const float* Wv = (const float*)d_in[5];
  const float* Wo = (const float*)d_in[6];
  const float* bq = (const float*)d_in[7];
  const float* bk = (const float*)d_in[8];
  const float* bv = (const float*)d_in[9];
  const float* bo = (const float*)d_in[10];

  const size_t NA = (size_t)4096 * 1024;   // 4M elems
  const size_t NW = (size_t)1024 * 1024;
  unsigned short* WqB = (unsigned short*)d_ws;   // weights bf16, contiguous
  unsigned short* WkB = WqB + NW;
  unsigned short* WvB = WkB + NW;
  unsigned short* WoB = WvB + NW;
  unsigned short* Qh  = WoB + NW;
  unsigned short* Kh  = Qh  + NA;
  unsigned short* Vt  = Kh  + NA;
  unsigned short* Y   = Vt  + NA;
  unsigned short* PO  = Y   + NA;          // 2 * 4M fp16 = 16 MB
  float2*         ML  = (float2*)(PO + 2 * NA);   // 2 * 64K float2 = 1 MB

  cvt_w<<<dim3(2048), 256, 0, stream>>>(Wq, Wk, Wv, Wo, WqB);

  qkv_gemm<<<dim3(32, 8, 3), 256, 0, stream>>>(q, k, v, WqB, WkB, WvB,
                                               bq, bk, bv, Qh, Kh, Vt);
  attn_kernel<<<dim3(8, 32, 2), 256, 0, stream>>>(Qh, Kh, Vt, PO, ML, 1024);
  combine_kernel<<<dim3(512), 256, 0, stream>>>(PO, ML, Y);
  out_gemm<<<dim3(32, 16), 256, 0, stream>>>(Y, WoB, bo, (float*)d_out);
}